// Round 1
// baseline (670.528 us; speedup 1.0000x reference)
//
#include <hip/hip_runtime.h>

#define HD 16  // hidden dim
#define NC 4   // num classes

// K1: degree count over targets (self-loop added as +1 later)
__global__ void k_degree(const int* __restrict__ col, int* __restrict__ cnt, int E) {
    int i = blockIdx.x * blockDim.x + threadIdx.x;
    if (i < E) atomicAdd(&cnt[col[i]], 1);
}

// K2: dinv = rsqrt(deg); seed s1 with layer-1 self-loop contribution dinv^2 * x
__global__ void k_dinv(const int* __restrict__ cnt, const float* __restrict__ x,
                       float* __restrict__ dinv, float* __restrict__ s1, int N) {
    int i = blockIdx.x * blockDim.x + threadIdx.x;
    if (i < N) {
        float d = rsqrtf((float)(cnt[i] + 1));
        dinv[i] = d;
        s1[i] = d * d * x[i];
    }
}

// K3: layer-1 scalar scatter: s1[c] += dinv[r]*dinv[c]*x[r]
__global__ void k_l1_scatter(const int* __restrict__ row, const int* __restrict__ col,
                             const float* __restrict__ dinv, const float* __restrict__ x,
                             float* __restrict__ s1, int E) {
    int i = blockIdx.x * blockDim.x + threadIdx.x;
    if (i < E) {
        int r = row[i], c = col[i];
        unsafeAtomicAdd(&s1[c], dinv[r] * dinv[c] * x[r]);
    }
}

// K4: seed agg2 with layer-2 self-loop: agg2[i][f] = dinv^2 * relu(s1*W1[f]+b1[f])
__global__ void k_h1_seed(const float* __restrict__ s1v, const float* __restrict__ dinv,
                          const float* __restrict__ W1, const float* __restrict__ b1,
                          float* __restrict__ agg2, int N) {
    int i = blockIdx.x * blockDim.x + threadIdx.x;
    if (i < N) {
        float s = s1v[i];
        float d2 = dinv[i] * dinv[i];
        #pragma unroll
        for (int f = 0; f < HD; ++f) {
            float h = fmaxf(fmaf(s, W1[f], b1[f]), 0.0f);
            agg2[i * HD + f] = d2 * h;
        }
    }
}

// K5: layer-2 scatter, 16 lanes per edge (lane f handles feature f).
// Recomputes h1r from scalar s1[r] instead of gathering a 64B vector.
__global__ void k_l2_scatter(const int* __restrict__ row, const int* __restrict__ col,
                             const float* __restrict__ dinv, const float* __restrict__ s1v,
                             const float* __restrict__ W1, const float* __restrict__ b1,
                             float* __restrict__ agg2, int E) {
    int t = blockIdx.x * blockDim.x + threadIdx.x;  // E*16 = 64M < 2^31
    int e = t >> 4;
    int f = t & (HD - 1);
    if (e < E) {
        int r = row[e], c = col[e];
        float nr = dinv[r] * dinv[c];
        float h = fmaxf(fmaf(s1v[r], W1[f], b1[f]), 0.0f);
        unsafeAtomicAdd(&agg2[c * HD + f], nr * h);
    }
}

// K6: per-node epilogue: h2 = relu(agg2 @ W2 + b2); out = h2 @ Wfc + bfc
__global__ void k_out(const float* __restrict__ agg2, const float* __restrict__ W2,
                      const float* __restrict__ b2, const float* __restrict__ Wfc,
                      const float* __restrict__ bfc, float* __restrict__ out, int N) {
    int i = blockIdx.x * blockDim.x + threadIdx.x;
    if (i >= N) return;
    // vector-load the 16-float aggregate (64B contiguous per thread)
    float a[HD];
    const float4* ap = (const float4*)(agg2 + (size_t)i * HD);
    #pragma unroll
    for (int q = 0; q < HD / 4; ++q) {
        float4 v = ap[q];
        a[q * 4 + 0] = v.x; a[q * 4 + 1] = v.y; a[q * 4 + 2] = v.z; a[q * 4 + 3] = v.w;
    }
    float o0 = bfc[0], o1 = bfc[1], o2 = bfc[2], o3 = bfc[3];
    #pragma unroll
    for (int f = 0; f < HD; ++f) {
        float h = b2[f];
        #pragma unroll
        for (int k = 0; k < HD; ++k) h = fmaf(a[k], W2[k * HD + f], h);
        h = fmaxf(h, 0.0f);
        o0 = fmaf(h, Wfc[f * NC + 0], o0);
        o1 = fmaf(h, Wfc[f * NC + 1], o1);
        o2 = fmaf(h, Wfc[f * NC + 2], o2);
        o3 = fmaf(h, Wfc[f * NC + 3], o3);
    }
    float4* op = (float4*)(out + (size_t)i * NC);
    *op = make_float4(o0, o1, o2, o3);
}

extern "C" void kernel_launch(void* const* d_in, const int* in_sizes, int n_in,
                              void* d_out, int out_size, void* d_ws, size_t ws_size,
                              hipStream_t stream) {
    const float* x   = (const float*)d_in[0];
    const int*   ei  = (const int*)d_in[1];   // [2, E] flat: first E = row (src), next E = col (dst)
    const float* W1  = (const float*)d_in[2]; // [1,16]
    const float* b1  = (const float*)d_in[3]; // [16]
    const float* W2  = (const float*)d_in[4]; // [16,16]
    const float* b2  = (const float*)d_in[5]; // [16]
    const float* Wfc = (const float*)d_in[6]; // [16,4]
    const float* bfc = (const float*)d_in[7]; // [4]
    float* out = (float*)d_out;

    const int N = in_sizes[0];        // 250000 (NUM_FEATURES=1)
    const int E = in_sizes[1] / 2;    // 4000000

    const int* row = ei;
    const int* col = ei + E;

    // workspace layout
    char* ws = (char*)d_ws;
    int*   cnt  = (int*)ws;                         // N ints
    float* dinv = (float*)(ws + (size_t)N * 4);     // N floats
    float* s1   = (float*)(ws + (size_t)N * 8);     // N floats
    float* agg2 = (float*)(ws + (size_t)N * 12);    // N*16 floats

    hipMemsetAsync(cnt, 0, (size_t)N * 4, stream);

    const int B = 256;
    k_degree<<<(E + B - 1) / B, B, 0, stream>>>(col, cnt, E);
    k_dinv<<<(N + B - 1) / B, B, 0, stream>>>(cnt, x, dinv, s1, N);
    k_l1_scatter<<<(E + B - 1) / B, B, 0, stream>>>(row, col, dinv, x, s1, E);
    k_h1_seed<<<(N + B - 1) / B, B, 0, stream>>>(s1, dinv, W1, b1, agg2, N);
    long long t5 = (long long)E * HD;
    k_l2_scatter<<<(int)((t5 + B - 1) / B), B, 0, stream>>>(row, col, dinv, s1, W1, b1, agg2, E);
    k_out<<<(N + B - 1) / B, B, 0, stream>>>(agg2, W2, b2, Wfc, bfc, out, N);
}